// Round 1
// 1644.838 us; speedup vs baseline: 1.0476x; 1.0476x over previous
//
#include <hip/hip_runtime.h>

// GRU decoder, bf16 MFMA. R8: attack the latency bound.
// rocprof R7: MfmaUtil 10%, VALUBusy 28.5%, Occupancy 23.7% (2 waves/SIMD)
// -> >60% issue-idle; plus 74 MB scratch writes (spills) thrashing L2
// (3.7 GB weight-stream re-fetch). Changes:
//  * 16 waves (1024 thr), each owns 16 gate-columns (n2 folded into wave id).
//    4 waves/SIMD doubles latency hiding; per-wave state ~110 regs < the
//    hard 128-reg cap a 1024-thread block imposes -> no spills.
//  * fast sigmoid/tanh via v_exp + v_rcp (libm tanhf + precise divides were
//    a big slice of VALUBusy).
//  * ONE barrier per step: hs/xs double-buffered by t parity, so epilogue
//    writes never collide with K-loop reads; waves' MFMA and VALU phases
//    overlap inside the barrier interval.
//  * cross-barrier prefetch of next step's kt=0 weight frags (t-invariant)
//    + split feat stage (issue load early, ds_write late) so the barrier's
//    vmcnt(0) drain is covered by epilogue VALU.
// sW layout and prep_swz unchanged from R7.

#define Bdim 8192
#define Tdim 96
#define Fdim 64
#define Hdim 256
#define BM   32
#define XS   72    // feat row stride (bf16): 64 + 8 pad
#define HS   264   // h row stride (bf16): 256 + 8 pad
#define OS   97    // outbuf row stride (floats)

typedef __attribute__((ext_vector_type(8))) short s16x8;
typedef __attribute__((ext_vector_type(4))) float f32x4;

#define MFMA __builtin_amdgcn_mfma_f32_16x16x32_bf16

__device__ __forceinline__ unsigned short f2bf(float f) {
    union { float f; unsigned u; } v; v.f = f;
    unsigned r = v.u + 0x7FFFu + ((v.u >> 16) & 1u);   // RNE
    return (unsigned short)(r >> 16);
}

__device__ __forceinline__ float sigm_fast(float x) {
    // 1/(1+e^-x); exp->inf / ->0 both give correct saturation via rcp
    return __builtin_amdgcn_rcpf(1.0f + __expf(-x));
}
__device__ __forceinline__ float tanh_fast(float x) {
    // 1 - 2/(e^{2x}+1); saturates correctly at +/-inf
    return 1.0f - 2.0f * __builtin_amdgcn_rcpf(1.0f + __expf(2.0f * x));
}

// ---- one-time weight conversion + B-fragment swizzle (unchanged) ----
// frag f = ((w*10 + kt)*3 + g)*2 + n2, lane l: 8 bf16 at sW[f*512 + l*8].
// lane holds B[k][n], k = kt*32 + (l>>4)*8 + j, n = g*256 + w*32 + n2*16 + (l&15).
// kt 0..7: B row k = Wr[k]; kt 8..9: B row = Wk[1 + (kt-8)*32 + (l>>4)*8 + j].
__global__ void prep_swz(const float* __restrict__ Wk, const float* __restrict__ Wr,
                         unsigned short* __restrict__ sW) {
    int idx = blockIdx.x * blockDim.x + threadIdx.x;
    if (idx >= 480 * 64) return;
    int lane = idx & 63, f = idx >> 6;
    int n2 = f & 1;
    int g  = (f >> 1) % 3;
    int kt = (f / 6) % 10;
    int w  = f / 60;
    int q = lane >> 4, cc = lane & 15;
    int n = g * 256 + w * 32 + n2 * 16 + cc;
    unsigned short* d = sW + (size_t)idx * 8;
#pragma unroll
    for (int j = 0; j < 8; ++j) {
        float v;
        if (kt < 8) v = Wr[(size_t)(kt * 32 + q * 8 + j) * 768 + n];
        else        v = Wk[(size_t)(1 + (kt - 8) * 32 + q * 8 + j) * 768 + n];
        d[j] = f2bf(v);
    }
}

__launch_bounds__(1024, 4)
__global__ void gru_mfma8(
    const float* __restrict__ feat,       // [B,T,F]
    const float* __restrict__ init_state, // [B,H]
    const float* __restrict__ init_inp,   // [B,1]
    const unsigned short* __restrict__ sW,
    const float* __restrict__ Wk,         // row 0 (prev_out rank-1 term)
    const float* __restrict__ ib, const float* __restrict__ rb,
    const float* __restrict__ dw, const float* __restrict__ db,
    float* __restrict__ out)              // [B,T,1]
{
    __shared__ __align__(16) unsigned short xs[2][BM * XS];  // feat, dbuf by t&1
    __shared__ __align__(16) unsigned short hs[2][BM * HS];  // h, dbuf by t&1
    __shared__ float wpart[2][16][BM];                       // dbuf by t&1
    __shared__ float outbuf[BM * OS];

    const int tid  = threadIdx.x;
    const int lane = tid & 63;
    const int wv   = tid >> 6;     // wave 0..15: 16 cols per gate
    const int q    = lane >> 4;
    const int c    = lane & 15;
    const int b0   = blockIdx.x * BM;
    const int col  = wv * 16 + c;  // column within each gate, 0..255

    // per-lane epilogue constants (n2 folded into wv)
    const float bz   = ib[col]       + rb[col];
    const float brr  = ib[256 + col] + rb[256 + col];
    const float bxh  = ib[512 + col];
    const float bhh  = rb[512 + col];
    const float wk0z = Wk[col];
    const float wk0r = Wk[256 + col];
    const float wk0h = Wk[512 + col];
    const float dwv  = dw[col];
    const float dbv  = db[0];

    // init h: fp32 in regs + bf16 in LDS (buffer 0)
    float hreg[2][4];     // [mt][i], single column per lane now
    float prevreg[2][4];  // [mt][i]
#pragma unroll
    for (int mt = 0; mt < 2; ++mt)
#pragma unroll
        for (int i = 0; i < 4; ++i) {
            int row = mt * 16 + q * 4 + i;
            prevreg[mt][i] = init_inp[b0 + row];
            float v = init_state[(size_t)(b0 + row) * Hdim + col];
            hreg[mt][i] = v;
            hs[0][row * HS + col] = f2bf(v);
        }

    // stage feat t=0 (1024 threads: 32 rows x 32 float2)
    {
        int r = tid >> 5, fi = tid & 31;
        float2 f = *(const float2*)&feat[((size_t)(b0 + r) * Tdim + 0) * Fdim + fi * 2];
        ushort2 p; p.x = f2bf(f.x); p.y = f2bf(f.y);
        *(ushort2*)&xs[0][r * XS + fi * 2] = p;
    }

    // frag addr: f = w*60 + (kt*3+g)*2 + n2, elements f*512 + lane*8
    const unsigned short* wp0 =
        sW + ((size_t)(wv >> 1) * 60 + (wv & 1)) * 512 + lane * 8;

    // prefetch kt=0 frags for t=0
    s16x8 bf[2][3];
#pragma unroll
    for (int g = 0; g < 3; ++g)
        bf[0][g] = *(const s16x8*)(wp0 + (size_t)g * 1024);

    __syncthreads();

    for (int t = 0; t < Tdim; ++t) {
        const unsigned short* hsp = hs[t & 1];
        const unsigned short* xsp = xs[t & 1];

        f32x4 az[2], ar[2], ax[2], ah[2];   // [mt]
#pragma unroll
        for (int mt = 0; mt < 2; ++mt) {
            az[mt] = (f32x4)0.0f; ar[mt] = (f32x4)0.0f;
            ax[mt] = (f32x4)0.0f; ah[mt] = (f32x4)0.0f;
        }

        // ---- unified K-loop, distance-1 prefetched weight fragments ----
#pragma unroll
        for (int kt = 0; kt < 10; ++kt) {
            if (kt + 1 < 10) {
#pragma unroll
                for (int g = 0; g < 3; ++g)
                    bf[(kt + 1) & 1][g] =
                        *(const s16x8*)(wp0 + (size_t)((kt + 1) * 3 + g) * 1024);
            }
            const s16x8* b = bf[kt & 1];
            s16x8 a0, a1;
            if (kt < 8) {
                a0 = *(const s16x8*)&hsp[c * HS + kt * 32 + q * 8];
                a1 = *(const s16x8*)&hsp[(16 + c) * HS + kt * 32 + q * 8];
            } else {
                a0 = *(const s16x8*)&xsp[c * XS + (kt - 8) * 32 + q * 8];
                a1 = *(const s16x8*)&xsp[(16 + c) * XS + (kt - 8) * 32 + q * 8];
            }
            az[0] = MFMA(a0, b[0], az[0], 0, 0, 0);
            az[1] = MFMA(a1, b[0], az[1], 0, 0, 0);
            ar[0] = MFMA(a0, b[1], ar[0], 0, 0, 0);
            ar[1] = MFMA(a1, b[1], ar[1], 0, 0, 0);
            if (kt < 8) {   // hh terms
                ah[0] = MFMA(a0, b[2], ah[0], 0, 0, 0);
                ah[1] = MFMA(a1, b[2], ah[1], 0, 0, 0);
            } else {        // xh terms
                ax[0] = MFMA(a0, b[2], ax[0], 0, 0, 0);
                ax[1] = MFMA(a1, b[2], ax[1], 0, 0, 0);
            }
        }

        // cross-barrier prefetch: next step's kt=0 frags (t-invariant data);
        // latency hidden under finish+epilogue VALU, drained at the barrier.
#pragma unroll
        for (int g = 0; g < 3; ++g)
            bf[0][g] = *(const s16x8*)(wp0 + (size_t)g * 1024);

        // split feat stage: issue the global load now, ds_write after epilogue
        float2 fnext;
        int fr = tid >> 5, ffi = tid & 31;
        if (t + 1 < Tdim)
            fnext = *(const float2*)&feat[((size_t)(b0 + fr) * Tdim + (t + 1)) * Fdim + ffi * 2];

        // ---- finish step t-1's dense output; broadcast prev_out ----
        if (t > 0) {
            int r = lane & 31;
            float s = dbv;
            const float (*wp)[BM] = wpart[(t - 1) & 1];
#pragma unroll
            for (int ww = 0; ww < 16; ++ww) s += wp[ww][r];
            if (wv == 0 && lane < 32) outbuf[r * OS + (t - 1)] = s;
#pragma unroll
            for (int mt = 0; mt < 2; ++mt)
#pragma unroll
                for (int i = 0; i < 4; ++i)
                    prevreg[mt][i] = __shfl(s, mt * 16 + q * 4 + i, 64);
        }

        // ---- epilogue: gates, h update, fused dense partial reduce ----
        unsigned short* hsn = hs[(t + 1) & 1];
#pragma unroll
        for (int mt = 0; mt < 2; ++mt)
#pragma unroll
            for (int i = 0; i < 4; ++i) {
                float pv = prevreg[mt][i];
                float zz = sigm_fast(az[mt][i] + bz + pv * wk0z);
                float rr = sigm_fast(ar[mt][i] + brr + pv * wk0r);
                float cd = tanh_fast(ax[mt][i] + bxh + pv * wk0h +
                                     rr * (ah[mt][i] + bhh));
                float hn = zz * hreg[mt][i] + (1.0f - zz) * cd;
                hreg[mt][i] = hn;
                hsn[(mt * 16 + q * 4 + i) * HS + col] = f2bf(hn);
                float s = hn * dwv;
                s += __shfl_xor(s, 1, 64);
                s += __shfl_xor(s, 2, 64);
                s += __shfl_xor(s, 4, 64);
                s += __shfl_xor(s, 8, 64);
                if (c == 0) wpart[t & 1][wv][mt * 16 + q * 4 + i] = s;
            }

        // late half of the feat stage
        if (t + 1 < Tdim) {
            ushort2 p; p.x = f2bf(fnext.x); p.y = f2bf(fnext.y);
            *(ushort2*)&xs[(t + 1) & 1][fr * XS + ffi * 2] = p;
        }
        __syncthreads();   // single barrier per step
    }

    // final dense output for t=95
    {
        int r = lane & 31;
        float s = dbv;
        const float (*wp)[BM] = wpart[(Tdim - 1) & 1];
#pragma unroll
        for (int ww = 0; ww < 16; ++ww) s += wp[ww][r];
        if (wv == 0 && lane < 32) outbuf[r * OS + (Tdim - 1)] = s;
    }
    __syncthreads();

    // coalesced dump: out[(b0+r)*96 + tt]
    for (int i = tid; i < BM * Tdim; i += 1024) {
        int r = i / Tdim, tt = i - r * Tdim;
        out[(size_t)b0 * Tdim + i] = outbuf[r * OS + tt];
    }
}

extern "C" void kernel_launch(void* const* d_in, const int* in_sizes, int n_in,
                              void* d_out, int out_size, void* d_ws, size_t ws_size,
                              hipStream_t stream) {
    const float* feat       = (const float*)d_in[0];
    const float* init_state = (const float*)d_in[1];
    const float* init_inp   = (const float*)d_in[2];
    const float* Wk         = (const float*)d_in[3];
    const float* Wr         = (const float*)d_in[4];
    const float* ib         = (const float*)d_in[5];
    const float* rb         = (const float*)d_in[6];
    const float* dw         = (const float*)d_in[7];
    const float* db         = (const float*)d_in[8];
    float* out              = (float*)d_out;

    unsigned short* sW = (unsigned short*)d_ws;   // 480 frags * 1 KB = 480 KB

    prep_swz<<<120, 256, 0, stream>>>(Wk, Wr, sW);
    gru_mfma8<<<Bdim / BM, 1024, 0, stream>>>(
        feat, init_state, init_inp, sW, Wk, ib, rb, dw, db, out);
}

// Round 2
// 1643.660 us; speedup vs baseline: 1.0483x; 1.0007x over previous
//
#include <hip/hip_runtime.h>

// GRU decoder, bf16 MFMA. R9: un-cap the registers.
// R8 post-mortem: __launch_bounds__(1024,4) capped arch VGPRs at 64
// (VGPR_Count=64 in rocprof) -> heavy in-loop scratch spills
// (WRITE_SIZE 152 MB vs 3.1 MB true output; FETCH 4.29 GB from spill
// reloads + L2 thrash of the 480 KB weight set). That kept the kernel
// scratch-latency-bound: MfmaUtil 10.8% despite occupancy 47%.
// Single change this round: __launch_bounds__(1024) (no waves-per-eu).
// A 1024-thread block must still fit 16 waves/CU -> backend caps at
// 128 regs/lane, which this kernel fits (~110), so occupancy stays
// 4 waves/SIMD with zero spills. Everything else identical to R8.

#define Bdim 8192
#define Tdim 96
#define Fdim 64
#define Hdim 256
#define BM   32
#define XS   72    // feat row stride (bf16): 64 + 8 pad
#define HS   264   // h row stride (bf16): 256 + 8 pad
#define OS   97    // outbuf row stride (floats)

typedef __attribute__((ext_vector_type(8))) short s16x8;
typedef __attribute__((ext_vector_type(4))) float f32x4;

#define MFMA __builtin_amdgcn_mfma_f32_16x16x32_bf16

__device__ __forceinline__ unsigned short f2bf(float f) {
    union { float f; unsigned u; } v; v.f = f;
    unsigned r = v.u + 0x7FFFu + ((v.u >> 16) & 1u);   // RNE
    return (unsigned short)(r >> 16);
}

__device__ __forceinline__ float sigm_fast(float x) {
    // 1/(1+e^-x); exp->inf / ->0 both give correct saturation via rcp
    return __builtin_amdgcn_rcpf(1.0f + __expf(-x));
}
__device__ __forceinline__ float tanh_fast(float x) {
    // 1 - 2/(e^{2x}+1); saturates correctly at +/-inf
    return 1.0f - 2.0f * __builtin_amdgcn_rcpf(1.0f + __expf(2.0f * x));
}

// ---- one-time weight conversion + B-fragment swizzle (unchanged) ----
// frag f = ((w*10 + kt)*3 + g)*2 + n2, lane l: 8 bf16 at sW[f*512 + l*8].
// lane holds B[k][n], k = kt*32 + (l>>4)*8 + j, n = g*256 + w*32 + n2*16 + (l&15).
// kt 0..7: B row k = Wr[k]; kt 8..9: B row = Wk[1 + (kt-8)*32 + (l>>4)*8 + j].
__global__ void prep_swz(const float* __restrict__ Wk, const float* __restrict__ Wr,
                         unsigned short* __restrict__ sW) {
    int idx = blockIdx.x * blockDim.x + threadIdx.x;
    if (idx >= 480 * 64) return;
    int lane = idx & 63, f = idx >> 6;
    int n2 = f & 1;
    int g  = (f >> 1) % 3;
    int kt = (f / 6) % 10;
    int w  = f / 60;
    int q = lane >> 4, cc = lane & 15;
    int n = g * 256 + w * 32 + n2 * 16 + cc;
    unsigned short* d = sW + (size_t)idx * 8;
#pragma unroll
    for (int j = 0; j < 8; ++j) {
        float v;
        if (kt < 8) v = Wr[(size_t)(kt * 32 + q * 8 + j) * 768 + n];
        else        v = Wk[(size_t)(1 + (kt - 8) * 32 + q * 8 + j) * 768 + n];
        d[j] = f2bf(v);
    }
}

__launch_bounds__(1024)
__global__ void gru_mfma9(
    const float* __restrict__ feat,       // [B,T,F]
    const float* __restrict__ init_state, // [B,H]
    const float* __restrict__ init_inp,   // [B,1]
    const unsigned short* __restrict__ sW,
    const float* __restrict__ Wk,         // row 0 (prev_out rank-1 term)
    const float* __restrict__ ib, const float* __restrict__ rb,
    const float* __restrict__ dw, const float* __restrict__ db,
    float* __restrict__ out)              // [B,T,1]
{
    __shared__ __align__(16) unsigned short xs[2][BM * XS];  // feat, dbuf by t&1
    __shared__ __align__(16) unsigned short hs[2][BM * HS];  // h, dbuf by t&1
    __shared__ float wpart[2][16][BM];                       // dbuf by t&1
    __shared__ float outbuf[BM * OS];

    const int tid  = threadIdx.x;
    const int lane = tid & 63;
    const int wv   = tid >> 6;     // wave 0..15: 16 cols per gate
    const int q    = lane >> 4;
    const int c    = lane & 15;
    const int b0   = blockIdx.x * BM;
    const int col  = wv * 16 + c;  // column within each gate, 0..255

    // per-lane epilogue constants (n2 folded into wv)
    const float bz   = ib[col]       + rb[col];
    const float brr  = ib[256 + col] + rb[256 + col];
    const float bxh  = ib[512 + col];
    const float bhh  = rb[512 + col];
    const float wk0z = Wk[col];
    const float wk0r = Wk[256 + col];
    const float wk0h = Wk[512 + col];
    const float dwv  = dw[col];
    const float dbv  = db[0];

    // init h: fp32 in regs + bf16 in LDS (buffer 0)
    float hreg[2][4];     // [mt][i], single column per lane
    float prevreg[2][4];  // [mt][i]
#pragma unroll
    for (int mt = 0; mt < 2; ++mt)
#pragma unroll
        for (int i = 0; i < 4; ++i) {
            int row = mt * 16 + q * 4 + i;
            prevreg[mt][i] = init_inp[b0 + row];
            float v = init_state[(size_t)(b0 + row) * Hdim + col];
            hreg[mt][i] = v;
            hs[0][row * HS + col] = f2bf(v);
        }

    // stage feat t=0 (1024 threads: 32 rows x 32 float2)
    {
        int r = tid >> 5, fi = tid & 31;
        float2 f = *(const float2*)&feat[((size_t)(b0 + r) * Tdim + 0) * Fdim + fi * 2];
        ushort2 p; p.x = f2bf(f.x); p.y = f2bf(f.y);
        *(ushort2*)&xs[0][r * XS + fi * 2] = p;
    }

    // frag addr: f = w*60 + (kt*3+g)*2 + n2, elements f*512 + lane*8
    const unsigned short* wp0 =
        sW + ((size_t)(wv >> 1) * 60 + (wv & 1)) * 512 + lane * 8;

    // prefetch kt=0 frags for t=0
    s16x8 bf[2][3];
#pragma unroll
    for (int g = 0; g < 3; ++g)
        bf[0][g] = *(const s16x8*)(wp0 + (size_t)g * 1024);

    __syncthreads();

    for (int t = 0; t < Tdim; ++t) {
        const unsigned short* hsp = hs[t & 1];
        const unsigned short* xsp = xs[t & 1];

        f32x4 az[2], ar[2], ax[2], ah[2];   // [mt]
#pragma unroll
        for (int mt = 0; mt < 2; ++mt) {
            az[mt] = (f32x4)0.0f; ar[mt] = (f32x4)0.0f;
            ax[mt] = (f32x4)0.0f; ah[mt] = (f32x4)0.0f;
        }

        // ---- unified K-loop, distance-1 prefetched weight fragments ----
#pragma unroll
        for (int kt = 0; kt < 10; ++kt) {
            if (kt + 1 < 10) {
#pragma unroll
                for (int g = 0; g < 3; ++g)
                    bf[(kt + 1) & 1][g] =
                        *(const s16x8*)(wp0 + (size_t)((kt + 1) * 3 + g) * 1024);
            }
            const s16x8* b = bf[kt & 1];
            s16x8 a0, a1;
            if (kt < 8) {
                a0 = *(const s16x8*)&hsp[c * HS + kt * 32 + q * 8];
                a1 = *(const s16x8*)&hsp[(16 + c) * HS + kt * 32 + q * 8];
            } else {
                a0 = *(const s16x8*)&xsp[c * XS + (kt - 8) * 32 + q * 8];
                a1 = *(const s16x8*)&xsp[(16 + c) * XS + (kt - 8) * 32 + q * 8];
            }
            az[0] = MFMA(a0, b[0], az[0], 0, 0, 0);
            az[1] = MFMA(a1, b[0], az[1], 0, 0, 0);
            ar[0] = MFMA(a0, b[1], ar[0], 0, 0, 0);
            ar[1] = MFMA(a1, b[1], ar[1], 0, 0, 0);
            if (kt < 8) {   // hh terms
                ah[0] = MFMA(a0, b[2], ah[0], 0, 0, 0);
                ah[1] = MFMA(a1, b[2], ah[1], 0, 0, 0);
            } else {        // xh terms
                ax[0] = MFMA(a0, b[2], ax[0], 0, 0, 0);
                ax[1] = MFMA(a1, b[2], ax[1], 0, 0, 0);
            }
        }

        // cross-barrier prefetch: next step's kt=0 frags (t-invariant data);
        // latency hidden under finish+epilogue VALU, drained at the barrier.
#pragma unroll
        for (int g = 0; g < 3; ++g)
            bf[0][g] = *(const s16x8*)(wp0 + (size_t)g * 1024);

        // split feat stage: issue the global load now, ds_write after epilogue
        float2 fnext;
        int fr = tid >> 5, ffi = tid & 31;
        if (t + 1 < Tdim)
            fnext = *(const float2*)&feat[((size_t)(b0 + fr) * Tdim + (t + 1)) * Fdim + ffi * 2];

        // ---- finish step t-1's dense output; broadcast prev_out ----
        if (t > 0) {
            int r = lane & 31;
            float s = dbv;
            const float (*wp)[BM] = wpart[(t - 1) & 1];
#pragma unroll
            for (int ww = 0; ww < 16; ++ww) s += wp[ww][r];
            if (wv == 0 && lane < 32) outbuf[r * OS + (t - 1)] = s;
#pragma unroll
            for (int mt = 0; mt < 2; ++mt)
#pragma unroll
                for (int i = 0; i < 4; ++i)
                    prevreg[mt][i] = __shfl(s, mt * 16 + q * 4 + i, 64);
        }

        // ---- epilogue: gates, h update, fused dense partial reduce ----
        unsigned short* hsn = hs[(t + 1) & 1];
#pragma unroll
        for (int mt = 0; mt < 2; ++mt)
#pragma unroll
            for (int i = 0; i < 4; ++i) {
                float pv = prevreg[mt][i];
                float zz = sigm_fast(az[mt][i] + bz + pv * wk0z);
                float rr = sigm_fast(ar[mt][i] + brr + pv * wk0r);
                float cd = tanh_fast(ax[mt][i] + bxh + pv * wk0h +
                                     rr * (ah[mt][i] + bhh));
                float hn = zz * hreg[mt][i] + (1.0f - zz) * cd;
                hreg[mt][i] = hn;
                hsn[(mt * 16 + q * 4 + i) * HS + col] = f2bf(hn);
                float s = hn * dwv;
                s += __shfl_xor(s, 1, 64);
                s += __shfl_xor(s, 2, 64);
                s += __shfl_xor(s, 4, 64);
                s += __shfl_xor(s, 8, 64);
                if (c == 0) wpart[t & 1][wv][mt * 16 + q * 4 + i] = s;
            }

        // late half of the feat stage
        if (t + 1 < Tdim) {
            ushort2 p; p.x = f2bf(fnext.x); p.y = f2bf(fnext.y);
            *(ushort2*)&xs[(t + 1) & 1][fr * XS + ffi * 2] = p;
        }
        __syncthreads();   // single barrier per step
    }

    // final dense output for t=95
    {
        int r = lane & 31;
        float s = dbv;
        const float (*wp)[BM] = wpart[(Tdim - 1) & 1];
#pragma unroll
        for (int ww = 0; ww < 16; ++ww) s += wp[ww][r];
        if (wv == 0 && lane < 32) outbuf[r * OS + (Tdim - 1)] = s;
    }
    __syncthreads();

    // coalesced dump: out[(b0+r)*96 + tt]
    for (int i = tid; i < BM * Tdim; i += 1024) {
        int r = i / Tdim, tt = i - r * Tdim;
        out[(size_t)b0 * Tdim + i] = outbuf[r * OS + tt];
    }
}

extern "C" void kernel_launch(void* const* d_in, const int* in_sizes, int n_in,
                              void* d_out, int out_size, void* d_ws, size_t ws_size,
                              hipStream_t stream) {
    const float* feat       = (const float*)d_in[0];
    const float* init_state = (const float*)d_in[1];
    const float* init_inp   = (const float*)d_in[2];
    const float* Wk         = (const float*)d_in[3];
    const float* Wr         = (const float*)d_in[4];
    const float* ib         = (const float*)d_in[5];
    const float* rb         = (const float*)d_in[6];
    const float* dw         = (const float*)d_in[7];
    const float* db         = (const float*)d_in[8];
    float* out              = (float*)d_out;

    unsigned short* sW = (unsigned short*)d_ws;   // 480 frags * 1 KB = 480 KB

    prep_swz<<<120, 256, 0, stream>>>(Wk, Wr, sW);
    gru_mfma9<<<Bdim / BM, 1024, 0, stream>>>(
        feat, init_state, init_inp, sW, Wk, ib, rb, dw, db, out);
}